// Round 1
// baseline (294.190 us; speedup 1.0000x reference)
//
#include <hip/hip_runtime.h>
#include <math.h>

#define STATE  65536
#define INPUT  32768
#define CONCAT 98304
#define H1_    100
#define H2_    50
#define NG     4

// ---------------------------------------------------------------------------
// k1: h1[r] = relu(dot(W1[r,:], concat(hyp,x)) + b1[r]),  r in [0,400)
// One block per row, 1024 threads, float4 fully-coalesced streaming.
// 65536 = 16*4096 and 32768 = 8*4096, so the concat boundary falls exactly
// between unrolled iterations -> no per-element select.
// ---------------------------------------------------------------------------
__global__ __launch_bounds__(1024) void k1_h1(
    const float* __restrict__ hyp, const float* __restrict__ x,
    const float* __restrict__ W1,  const float* __restrict__ b1,
    float* __restrict__ h1)
{
    const int row = blockIdx.x;
    const int tid = threadIdx.x;
    const float* __restrict__ Wrow = W1 + (size_t)row * CONCAT;

    float4 acc = make_float4(0.f, 0.f, 0.f, 0.f);

    #pragma unroll
    for (int it = 0; it < 16; ++it) {              // hypotesis part
        const int i = it * 4096 + tid * 4;
        const float4 w = *reinterpret_cast<const float4*>(Wrow + i);
        const float4 v = *reinterpret_cast<const float4*>(hyp + i);
        acc.x = fmaf(w.x, v.x, acc.x);
        acc.y = fmaf(w.y, v.y, acc.y);
        acc.z = fmaf(w.z, v.z, acc.z);
        acc.w = fmaf(w.w, v.w, acc.w);
    }
    #pragma unroll
    for (int it = 0; it < 8; ++it) {               // x part
        const int i = it * 4096 + tid * 4;
        const float4 w = *reinterpret_cast<const float4*>(Wrow + STATE + i);
        const float4 v = *reinterpret_cast<const float4*>(x + i);
        acc.x = fmaf(w.x, v.x, acc.x);
        acc.y = fmaf(w.y, v.y, acc.y);
        acc.z = fmaf(w.z, v.z, acc.z);
        acc.w = fmaf(w.w, v.w, acc.w);
    }

    float sum = (acc.x + acc.y) + (acc.z + acc.w);

    // wave64 reduce
    #pragma unroll
    for (int off = 32; off > 0; off >>= 1)
        sum += __shfl_down(sum, off, 64);

    __shared__ float wsum[16];
    if ((tid & 63) == 0) wsum[tid >> 6] = sum;
    __syncthreads();

    if (tid < 16) {
        float s = wsum[tid];
        s += __shfl_down(s, 8, 64);
        s += __shfl_down(s, 4, 64);
        s += __shfl_down(s, 2, 64);
        s += __shfl_down(s, 1, 64);
        if (tid == 0) h1[row] = fmaxf(s + b1[row], 0.f);
    }
}

// ---------------------------------------------------------------------------
// k3: per block (256 thr): stage h1 -> LDS, recompute h2 (tiny, W2 L2-hot),
// then wave g computes z[g][s] for 64 consecutive s via 50-length dots on
// contiguous W3 rows; wave 0 fuses gates + elementwise LSTM update.
// out[0..65535] = new_hypotesis, out[65536..131071] = new_cell_state.
// ---------------------------------------------------------------------------
__global__ __launch_bounds__(256) void k3_out(
    const float* __restrict__ h1, const float* __restrict__ W2,
    const float* __restrict__ b2, const float* __restrict__ W3,
    const float* __restrict__ b3, const float* __restrict__ cprev,
    float* __restrict__ out)
{
    __shared__ float h1s[NG * H1_];   // 400
    __shared__ float h2s[NG * H2_];   // 200
    __shared__ float zsh[NG * 64];    // 256

    const int tid = threadIdx.x;

    for (int i = tid; i < NG * H1_; i += 256) h1s[i] = h1[i];
    __syncthreads();

    if (tid < NG * H2_) {
        const int g = tid / H2_;
        const float* __restrict__ Wr = W2 + tid * H1_;   // 400B-aligned
        float4 a = make_float4(0.f, 0.f, 0.f, 0.f);
        #pragma unroll
        for (int j = 0; j < H1_ / 4; ++j) {
            const float4 w = *reinterpret_cast<const float4*>(Wr + 4 * j);
            a.x = fmaf(w.x, h1s[g * H1_ + 4 * j + 0], a.x);
            a.y = fmaf(w.y, h1s[g * H1_ + 4 * j + 1], a.y);
            a.z = fmaf(w.z, h1s[g * H1_ + 4 * j + 2], a.z);
            a.w = fmaf(w.w, h1s[g * H1_ + 4 * j + 3], a.w);
        }
        const float v = (a.x + a.y) + (a.z + a.w) + b2[tid];
        h2s[tid] = fmaxf(v, 0.f);
    }
    __syncthreads();

    const int g    = tid >> 6;
    const int lane = tid & 63;
    const int s    = blockIdx.x * 64 + lane;
    const float* __restrict__ Wr = W3 + ((size_t)g * STATE + s) * H2_; // 8B-aligned
    float a0 = 0.f, a1 = 0.f;
    #pragma unroll
    for (int k = 0; k < H2_; k += 2) {
        const float2 w = *reinterpret_cast<const float2*>(Wr + k);
        a0 = fmaf(w.x, h2s[g * H2_ + k + 0], a0);
        a1 = fmaf(w.y, h2s[g * H2_ + k + 1], a1);
    }
    zsh[g * 64 + lane] = a0 + a1 + b3[(size_t)g * STATE + s];
    __syncthreads();

    if (tid < 64) {
        const int ss = blockIdx.x * 64 + tid;
        const float zf = zsh[0 * 64 + tid];
        const float zi = zsh[1 * 64 + tid];
        const float zc = zsh[2 * 64 + tid];
        const float zo = zsh[3 * 64 + tid];
        const float fg = 1.f / (1.f + expf(-zf));
        const float ig = 1.f / (1.f + expf(-zi));
        const float ch = tanhf(zc);
        const float og = 1.f / (1.f + expf(-zo));
        const float nc = fg * cprev[ss] + ig * ch;
        const float nh = tanhf(nc) * og;
        out[ss]         = nh;   // new_hypotesis
        out[STATE + ss] = nc;   // new_cell_state
    }
}

extern "C" void kernel_launch(void* const* d_in, const int* in_sizes, int n_in,
                              void* d_out, int out_size, void* d_ws, size_t ws_size,
                              hipStream_t stream) {
    const float* cprev = (const float*)d_in[0];
    const float* hyp   = (const float*)d_in[1];
    const float* x     = (const float*)d_in[2];
    const float* W1    = (const float*)d_in[3];
    const float* b1    = (const float*)d_in[4];
    const float* W2    = (const float*)d_in[5];
    const float* b2    = (const float*)d_in[6];
    const float* W3    = (const float*)d_in[7];
    const float* b3    = (const float*)d_in[8];
    float* out = (float*)d_out;
    float* h1  = (float*)d_ws;   // 400 floats of scratch

    k1_h1<<<NG * H1_, 1024, 0, stream>>>(hyp, x, W1, b1, h1);
    k3_out<<<STATE / 64, 256, 0, stream>>>(h1, W2, b2, W3, b3, cprev, out);
}

// Round 2
// 285.163 us; speedup vs baseline: 1.0317x; 1.0317x over previous
//
#include <hip/hip_runtime.h>
#include <math.h>

#define STATE   65536
#define INPUT   32768
#define CONCAT  98304
#define H1_     100
#define H2_     50
#define NG      4
#define NROWS   (NG * H1_)      // 400
#define SEGS    6
#define SEGCOLS 16384           // 4 segs cover hyp (65536), 2 segs cover x (32768)

// ---------------------------------------------------------------------------
// k1: partial dot products of W1 rows against concat(hyp, x).
// Grid: SEGS*NROWS = 2400 blocks x 256 threads, seg-major so concurrently
// resident blocks share the same 64KB vector segment via L2.
// Each block computes dot(W1[row, seg*16384 : (seg+1)*16384], vec_seg) and
// writes one float partial to ws[seg*NROWS + row]. No atomics, no init.
// ---------------------------------------------------------------------------
__global__ __launch_bounds__(256) void k1_partial(
    const float* __restrict__ hyp, const float* __restrict__ x,
    const float* __restrict__ W1,  float* __restrict__ part)
{
    const int bid = blockIdx.x;
    const int seg = bid / NROWS;          // 0..5 (const-div -> magic mul)
    const int row = bid - seg * NROWS;
    const int tid = threadIdx.x;

    const float* __restrict__ vec =
        (seg < 4) ? (hyp + seg * SEGCOLS) : (x + (seg - 4) * SEGCOLS);
    const float* __restrict__ w = W1 + (size_t)row * CONCAT + seg * SEGCOLS;

    float4 acc = make_float4(0.f, 0.f, 0.f, 0.f);
    #pragma unroll
    for (int it = 0; it < 16; ++it) {     // 16384 cols / (256 thr * 4) = 16
        const int i = it * 1024 + tid * 4;
        const float4 wv = *reinterpret_cast<const float4*>(w + i);
        const float4 vv = *reinterpret_cast<const float4*>(vec + i);
        acc.x = fmaf(wv.x, vv.x, acc.x);
        acc.y = fmaf(wv.y, vv.y, acc.y);
        acc.z = fmaf(wv.z, vv.z, acc.z);
        acc.w = fmaf(wv.w, vv.w, acc.w);
    }
    float sum = (acc.x + acc.y) + (acc.z + acc.w);

    #pragma unroll
    for (int off = 32; off > 0; off >>= 1)
        sum += __shfl_down(sum, off, 64);

    __shared__ float wsum[4];
    if ((tid & 63) == 0) wsum[tid >> 6] = sum;
    __syncthreads();
    if (tid == 0)
        part[bid] = (wsum[0] + wsum[1]) + (wsum[2] + wsum[3]);
}

// ---------------------------------------------------------------------------
// k3: per block (256 thr): gather h1 = relu(sum(partials)+b1) -> LDS,
// recompute h2 (tiny, W2 L2-hot), then wave g computes z[g][s] for 64
// consecutive s via 50-length dots on contiguous W3 rows; wave 0 fuses
// gates + elementwise LSTM update.
// out[0..65535] = new_hypotesis, out[65536..131071] = new_cell_state.
// ---------------------------------------------------------------------------
__global__ __launch_bounds__(256) void k3_out(
    const float* __restrict__ part, const float* __restrict__ b1,
    const float* __restrict__ W2,   const float* __restrict__ b2,
    const float* __restrict__ W3,   const float* __restrict__ b3,
    const float* __restrict__ cprev, float* __restrict__ out)
{
    __shared__ float h1s[NROWS];      // 400
    __shared__ float h2s[NG * H2_];   // 200
    __shared__ float zsh[NG * 64];    // 256

    const int tid = threadIdx.x;

    for (int i = tid; i < NROWS; i += 256) {
        float s = b1[i];
        #pragma unroll
        for (int seg = 0; seg < SEGS; ++seg) s += part[seg * NROWS + i];
        h1s[i] = fmaxf(s, 0.f);
    }
    __syncthreads();

    if (tid < NG * H2_) {
        const int g = tid / H2_;
        const float* __restrict__ Wr = W2 + tid * H1_;   // 400B-aligned
        float4 a = make_float4(0.f, 0.f, 0.f, 0.f);
        #pragma unroll
        for (int j = 0; j < H1_ / 4; ++j) {
            const float4 w = *reinterpret_cast<const float4*>(Wr + 4 * j);
            a.x = fmaf(w.x, h1s[g * H1_ + 4 * j + 0], a.x);
            a.y = fmaf(w.y, h1s[g * H1_ + 4 * j + 1], a.y);
            a.z = fmaf(w.z, h1s[g * H1_ + 4 * j + 2], a.z);
            a.w = fmaf(w.w, h1s[g * H1_ + 4 * j + 3], a.w);
        }
        const float v = (a.x + a.y) + (a.z + a.w) + b2[tid];
        h2s[tid] = fmaxf(v, 0.f);
    }
    __syncthreads();

    const int g    = tid >> 6;
    const int lane = tid & 63;
    const int s    = blockIdx.x * 64 + lane;
    const float* __restrict__ Wr = W3 + ((size_t)g * STATE + s) * H2_; // 8B-aligned
    float a0 = 0.f, a1 = 0.f;
    #pragma unroll
    for (int k = 0; k < H2_; k += 2) {
        const float2 w = *reinterpret_cast<const float2*>(Wr + k);
        a0 = fmaf(w.x, h2s[g * H2_ + k + 0], a0);
        a1 = fmaf(w.y, h2s[g * H2_ + k + 1], a1);
    }
    zsh[g * 64 + lane] = a0 + a1 + b3[(size_t)g * STATE + s];
    __syncthreads();

    if (tid < 64) {
        const int ss = blockIdx.x * 64 + tid;
        const float zf = zsh[0 * 64 + tid];
        const float zi = zsh[1 * 64 + tid];
        const float zc = zsh[2 * 64 + tid];
        const float zo = zsh[3 * 64 + tid];
        const float fg = 1.f / (1.f + expf(-zf));
        const float ig = 1.f / (1.f + expf(-zi));
        const float ch = tanhf(zc);
        const float og = 1.f / (1.f + expf(-zo));
        const float nc = fg * cprev[ss] + ig * ch;
        const float nh = tanhf(nc) * og;
        out[ss]         = nh;   // new_hypotesis
        out[STATE + ss] = nc;   // new_cell_state
    }
}

extern "C" void kernel_launch(void* const* d_in, const int* in_sizes, int n_in,
                              void* d_out, int out_size, void* d_ws, size_t ws_size,
                              hipStream_t stream) {
    const float* cprev = (const float*)d_in[0];
    const float* hyp   = (const float*)d_in[1];
    const float* x     = (const float*)d_in[2];
    const float* W1    = (const float*)d_in[3];
    const float* b1    = (const float*)d_in[4];
    const float* W2    = (const float*)d_in[5];
    const float* b2    = (const float*)d_in[6];
    const float* W3    = (const float*)d_in[7];
    const float* b3    = (const float*)d_in[8];
    float* out  = (float*)d_out;
    float* part = (float*)d_ws;    // SEGS*NROWS = 2400 floats of scratch

    k1_partial<<<SEGS * NROWS, 256, 0, stream>>>(hyp, x, W1, part);
    k3_out<<<STATE / 64, 256, 0, stream>>>(part, b1, W2, b2, W3, b3, cprev, out);
}

// Round 4
// 282.682 us; speedup vs baseline: 1.0407x; 1.0088x over previous
//
#include <hip/hip_runtime.h>
#include <math.h>

#define STATE   65536
#define INPUT   32768
#define CONCAT  98304
#define H1_     100
#define H2_     50
#define NG      4
#define NROWS   (NG * H1_)      // 400
#define SEGS    6
#define SEGCOLS 16384           // 4 segs cover hyp (65536), 2 segs cover x (32768)
#define NTILES  (SEGS * NROWS)  // 2400
#define NBLK    1200            // 2 tiles per block, all co-resident (<=2048)

// ---------------------------------------------------------------------------
// k1: partial dot products of W1 rows against concat(hyp, x).
// 1200 blocks x 256 threads, exactly 2 tiles per block (perfect balance, no
// straggler dispatch round). Tile t = (seg, row); seg-major so co-resident
// blocks share the same 64KB vector segment via L2.
// part[t] = dot(W1[row, seg*16384 : (seg+1)*16384], vec_seg)
// ---------------------------------------------------------------------------
__global__ __launch_bounds__(256) void k1_partial(
    const float* __restrict__ hyp, const float* __restrict__ x,
    const float* __restrict__ W1,  float* __restrict__ part)
{
    const int tid = threadIdx.x;
    __shared__ float wsum[4];

    #pragma unroll
    for (int rep = 0; rep < 2; ++rep) {
        const int t   = blockIdx.x + rep * NBLK;
        const int seg = t / NROWS;            // 0..5 (const-div -> magic mul)
        const int row = t - seg * NROWS;

        const float* __restrict__ vec =
            (seg < 4) ? (hyp + seg * SEGCOLS) : (x + (seg - 4) * SEGCOLS);
        const float* __restrict__ w = W1 + (size_t)row * CONCAT + seg * SEGCOLS;

        float4 acc = make_float4(0.f, 0.f, 0.f, 0.f);
        #pragma unroll
        for (int it = 0; it < 16; ++it) {     // 16384 cols / (256 thr * 4)
            const int i = it * 1024 + tid * 4;
            const float4 wv = *reinterpret_cast<const float4*>(w + i);
            const float4 vv = *reinterpret_cast<const float4*>(vec + i);
            acc.x = fmaf(wv.x, vv.x, acc.x);
            acc.y = fmaf(wv.y, vv.y, acc.y);
            acc.z = fmaf(wv.z, vv.z, acc.z);
            acc.w = fmaf(wv.w, vv.w, acc.w);
        }
        float sum = (acc.x + acc.y) + (acc.z + acc.w);

        #pragma unroll
        for (int off = 32; off > 0; off >>= 1)
            sum += __shfl_down(sum, off, 64);

        if ((tid & 63) == 0) wsum[tid >> 6] = sum;
        __syncthreads();
        if (tid == 0) part[t] = (wsum[0] + wsum[1]) + (wsum[2] + wsum[3]);
        __syncthreads();                      // protect wsum for rep 1
    }
}

// ---------------------------------------------------------------------------
// k3: per block (256 thr): gather h1 = relu(sum(partials)+b1) -> LDS,
// recompute h2 (tiny, W2 L2-hot), then wave g computes z[g][s] for 64
// consecutive s via 50-length dots on contiguous W3 rows; wave 0 fuses
// gates + elementwise LSTM update.
// out[0..65535] = new_hypotesis, out[65536..131071] = new_cell_state.
// ---------------------------------------------------------------------------
__global__ __launch_bounds__(256) void k3_out(
    const float* __restrict__ part, const float* __restrict__ b1,
    const float* __restrict__ W2,   const float* __restrict__ b2,
    const float* __restrict__ W3,   const float* __restrict__ b3,
    const float* __restrict__ cprev, float* __restrict__ out)
{
    __shared__ float h1s[NROWS];      // 400
    __shared__ float h2s[NG * H2_];   // 200
    __shared__ float zsh[NG * 64];    // 256

    const int tid = threadIdx.x;

    for (int i = tid; i < NROWS; i += 256) {
        float s = b1[i];
        #pragma unroll
        for (int seg = 0; seg < SEGS; ++seg) s += part[seg * NROWS + i];
        h1s[i] = fmaxf(s, 0.f);
    }
    __syncthreads();

    if (tid < NG * H2_) {
        const int g = tid / H2_;
        const float* __restrict__ Wr = W2 + tid * H1_;   // 400B-aligned
        float4 a = make_float4(0.f, 0.f, 0.f, 0.f);
        #pragma unroll
        for (int j = 0; j < H1_ / 4; ++j) {
            const float4 w = *reinterpret_cast<const float4*>(Wr + 4 * j);
            a.x = fmaf(w.x, h1s[g * H1_ + 4 * j + 0], a.x);
            a.y = fmaf(w.y, h1s[g * H1_ + 4 * j + 1], a.y);
            a.z = fmaf(w.z, h1s[g * H1_ + 4 * j + 2], a.z);
            a.w = fmaf(w.w, h1s[g * H1_ + 4 * j + 3], a.w);
        }
        const float v = (a.x + a.y) + (a.z + a.w) + b2[tid];
        h2s[tid] = fmaxf(v, 0.f);
    }
    __syncthreads();

    const int g    = tid >> 6;
    const int lane = tid & 63;
    const int s    = blockIdx.x * 64 + lane;
    const float* __restrict__ Wr = W3 + ((size_t)g * STATE + s) * H2_; // 8B-aligned
    float a0 = 0.f, a1 = 0.f;
    #pragma unroll
    for (int k = 0; k < H2_; k += 2) {
        const float2 w = *reinterpret_cast<const float2*>(Wr + k);
        a0 = fmaf(w.x, h2s[g * H2_ + k + 0], a0);
        a1 = fmaf(w.y, h2s[g * H2_ + k + 1], a1);
    }
    zsh[g * 64 + lane] = a0 + a1 + b3[(size_t)g * STATE + s];
    __syncthreads();

    if (tid < 64) {
        const int ss = blockIdx.x * 64 + tid;
        const float zf = zsh[0 * 64 + tid];
        const float zi = zsh[1 * 64 + tid];
        const float zc = zsh[2 * 64 + tid];
        const float zo = zsh[3 * 64 + tid];
        const float fg = 1.f / (1.f + expf(-zf));
        const float ig = 1.f / (1.f + expf(-zi));
        const float ch = tanhf(zc);
        const float og = 1.f / (1.f + expf(-zo));
        const float nc = fg * cprev[ss] + ig * ch;
        const float nh = tanhf(nc) * og;
        out[ss]         = nh;   // new_hypotesis
        out[STATE + ss] = nc;   // new_cell_state
    }
}

extern "C" void kernel_launch(void* const* d_in, const int* in_sizes, int n_in,
                              void* d_out, int out_size, void* d_ws, size_t ws_size,
                              hipStream_t stream) {
    const float* cprev = (const float*)d_in[0];
    const float* hyp   = (const float*)d_in[1];
    const float* x     = (const float*)d_in[2];
    const float* W1    = (const float*)d_in[3];
    const float* b1    = (const float*)d_in[4];
    const float* W2    = (const float*)d_in[5];
    const float* b2    = (const float*)d_in[6];
    const float* W3    = (const float*)d_in[7];
    const float* b3    = (const float*)d_in[8];
    float* out  = (float*)d_out;
    float* part = (float*)d_ws;    // NTILES = 2400 floats of scratch

    k1_partial<<<NBLK, 256, 0, stream>>>(hyp, x, W1, part);
    k3_out<<<STATE / 64, 256, 0, stream>>>(part, b1, W2, b2, W3, b3, cprev, out);
}